// Round 10
// baseline (360.162 us; speedup 1.0000x reference)
//
#include <hip/hip_runtime.h>
#include <hip/hip_bf16.h>

// EuclideanAttention: B=2, S=2048, D=1024, H=16, Hd=64. fp32 in/out.
#define NUM_B   2
#define SEQ     2048
#define DMODEL  1024
#define NH      16
#define HD      64
#define M_TOT   (NUM_B * SEQ)      // 4096
#define N_QKV   (3 * DMODEL)       // 3072
#define LOG2E   1.4426950408889634f
#define EXP_BIAS 96.0f             // round-7 verified softmax bias

typedef __attribute__((ext_vector_type(8))) short short8v;
typedef __attribute__((ext_vector_type(4))) float float4v;
typedef unsigned short ushort_t;

__device__ __forceinline__ ushort_t f2bf(float x) {
    unsigned u = __builtin_bit_cast(unsigned, x);
    u = u + 0x7FFFu + ((u >> 16) & 1u);
    return (ushort_t)(u >> 16);
}
__device__ __forceinline__ float bf2f(ushort_t h) {
    unsigned u = ((unsigned)h) << 16;
    return __builtin_bit_cast(float, u);
}
__device__ __forceinline__ void gll16(const void* g, void* l) {
    __builtin_amdgcn_global_load_lds(
        (const __attribute__((address_space(1))) unsigned int*)g,
        (__attribute__((address_space(3))) unsigned int*)l, 16, 0, 0);
}
__device__ __forceinline__ int sw4(int r) { return (r & 3) ^ ((r >> 2) & 3); }

// ---------------------------------------------------------------------------
// Prep: W_qkv -> WqT hi/lo; W_o -> WoT; (PRE) X -> Xhi/Xlo bf16 split.
// ---------------------------------------------------------------------------
__global__ __launch_bounds__(256) void prep_kernel(
    const float* __restrict__ Wq, const float* __restrict__ Wo,
    const float* __restrict__ Xf,
    ushort_t* __restrict__ WqT_hi, ushort_t* __restrict__ WqT_lo,
    ushort_t* __restrict__ WoT,
    ushort_t* __restrict__ Xhi, ushort_t* __restrict__ Xlo)
{
    const int bid = blockIdx.x;
    const int t = threadIdx.x;

    if (bid >= 1024) {             // X split: 1024 blocks x 4096 elements
        size_t base = (size_t)(bid - 1024) * 4096 + t * 16;
        float xs[16];
        *(float4v*)&xs[0]  = *(const float4v*)(Xf + base);
        *(float4v*)&xs[4]  = *(const float4v*)(Xf + base + 4);
        *(float4v*)&xs[8]  = *(const float4v*)(Xf + base + 8);
        *(float4v*)&xs[12] = *(const float4v*)(Xf + base + 12);
        short8v h0, h1, l0, l1;
        #pragma unroll
        for (int e = 0; e < 8; e++) {
            ushort_t a = f2bf(xs[e]), b = f2bf(xs[8 + e]);
            h0[e] = (short)a; h1[e] = (short)b;
            l0[e] = (short)f2bf(xs[e] - bf2f(a));
            l1[e] = (short)f2bf(xs[8 + e] - bf2f(b));
        }
        *(short8v*)(Xhi + base) = h0; *(short8v*)(Xhi + base + 8) = h1;
        *(short8v*)(Xlo + base) = l0; *(short8v*)(Xlo + base + 8) = l1;
        return;
    }

    __shared__ float Tf[64][65];
    const float* src; ushort_t *dhi, *dlo; int N, k0, n0;
    if (bid < 768) {
        int kt = bid / 48, nt = bid % 48;
        src = Wq; N = N_QKV; dhi = WqT_hi; dlo = WqT_lo;
        k0 = kt * 64; n0 = nt * 64;
    } else {
        int tid = bid - 768;
        int kt = tid >> 4, nt = tid & 15;
        src = Wo; N = DMODEL; dhi = WoT; dlo = nullptr;
        k0 = kt * 64; n0 = nt * 64;
    }
    {
        int r = t >> 2, c0 = (t & 3) * 16;
        const float* srow = src + (size_t)(k0 + r) * N + n0 + c0;
        #pragma unroll
        for (int u = 0; u < 4; u++) {
            float4v f = *(const float4v*)(srow + 4 * u);
            #pragma unroll
            for (int e = 0; e < 4; e++) Tf[r][c0 + 4 * u + e] = f[e];
        }
    }
    __syncthreads();
    {
        int nl = t >> 2, kc = (t & 3) * 16;
        short8v h0, h1, l0, l1;
        #pragma unroll
        for (int e = 0; e < 8; e++) {
            float x0 = Tf[kc + e][nl];
            float x1 = Tf[kc + 8 + e][nl];
            ushort_t a = f2bf(x0), b = f2bf(x1);
            h0[e] = (short)a; h1[e] = (short)b;
            l0[e] = (short)f2bf(x0 - bf2f(a));
            l1[e] = (short)f2bf(x1 - bf2f(b));
        }
        ushort_t* o = dhi + (size_t)(n0 + nl) * 1024 + k0 + kc;
        *(short8v*)o = h0; *(short8v*)(o + 8) = h1;
        if (dlo) {
            ushort_t* o2 = dlo + (size_t)(n0 + nl) * 1024 + k0 + kc;
            *(short8v*)o2 = l0; *(short8v*)(o2 + 8) = l1;
        }
    }
}

// ---------------------------------------------------------------------------
// QKV MFMA GEMM (round-8 verified; unchanged).
// ---------------------------------------------------------------------------
template<bool PRE>
__global__ __launch_bounds__(256) void qkv_mfma_kernel(
    const float* __restrict__ X,
    const ushort_t* __restrict__ Xhi, const ushort_t* __restrict__ Xlo,
    const ushort_t* __restrict__ WqT_hi, const ushort_t* __restrict__ WqT_lo,
    const float* __restrict__ bias,
    ushort_t* __restrict__ Qhi, ushort_t* __restrict__ Qlo,
    ushort_t* __restrict__ Khi, ushort_t* __restrict__ Klo,
    ushort_t* __restrict__ Vout,
    float* __restrict__ Qsq, float* __restrict__ Ksq)
{
    __shared__ ushort_t AS2[2 * 128 * 32];
    __shared__ ushort_t BS [2 * 128 * 32];
    const int LO = 128 * 32;
    const int t = threadIdx.x;
    const int w = t >> 6, lane = t & 63;
    const int quad = (t >> 4) & 3, ln = t & 15;
    const int wr = w >> 1, wc = w & 1;
    const int m0 = blockIdx.y * 128, n0 = blockIdx.x * 128;
    const int g = blockIdx.x * 2 + wc;
    const int h = g / 3, part = g % 3;

    const ushort_t* gA[2]; ushort_t* lA[2];
    const float* aptr = nullptr;
    ushort_t *ast_hi0, *ast_hi1, *ast_lo0, *ast_lo1;
    size_t xlo_off = 0;
    if constexpr (PRE) {
        #pragma unroll
        for (int i = 0; i < 2; i++) {
            int c = 256 * i + 64 * w + lane;
            int r = c >> 2, kbp = c & 3;
            gA[i] = Xhi + (size_t)(m0 + r) * 1024 + 8 * (kbp ^ sw4(r));
            lA[i] = &AS2[(256 * i + 64 * w) * 8];
        }
        xlo_off = (size_t)(Xlo - Xhi);
    } else {
        const int arow = t >> 1, akh = t & 1;
        aptr = X + (size_t)(m0 + arow) * DMODEL + 16 * akh;
        const int asw = sw4(arow);
        ast_hi0 = &AS2[arow * 32 + (((2 * akh) ^ asw) << 3)];
        ast_hi1 = &AS2[arow * 32 + (((2 * akh + 1) ^ asw) << 3)];
        ast_lo0 = &AS2[LO + arow * 32 + (((2 * akh) ^ asw) << 3)];
        ast_lo1 = &AS2[LO + arow * 32 + (((2 * akh + 1) ^ asw) << 3)];
    }

    const ushort_t* gB[2]; ushort_t* lB[2];
    #pragma unroll
    for (int i = 0; i < 2; i++) {
        int c = 256 * i + 64 * w + lane;
        int n = c >> 2, kbp = c & 3;
        gB[i] = WqT_hi + (size_t)(n0 + n) * 1024 + 8 * (kbp ^ sw4(n));
        lB[i] = &BS[(256 * i + 64 * w) * 8];
    }
    const size_t lo_goff = (size_t)(WqT_lo - WqT_hi);

    int aoff[4], boff[4];
    #pragma unroll
    for (int i = 0; i < 4; i++) {
        int m_l = 64 * wr + 16 * i + ln;
        aoff[i] = m_l * 32 + ((quad ^ sw4(m_l)) << 3);
        int n_l = 64 * wc + 16 * i + ln;
        boff[i] = n_l * 32 + ((quad ^ sw4(n_l)) << 3);
    }

    float4v acc[4][4];
    #pragma unroll
    for (int i = 0; i < 4; i++)
        #pragma unroll
        for (int j = 0; j < 4; j++) acc[i][j] = (float4v){0.f, 0.f, 0.f, 0.f};

    for (int k0 = 0; k0 < DMODEL; k0 += 32) {
        __syncthreads();
        #pragma unroll
        for (int i = 0; i < 2; i++) {
            gll16(gB[i] + k0, lB[i]);
            gll16(gB[i] + k0 + lo_goff, lB[i] + LO);
        }
        if constexpr (PRE) {
            #pragma unroll
            for (int i = 0; i < 2; i++) {
                gll16(gA[i] + k0, lA[i]);
                gll16(gA[i] + k0 + xlo_off, lA[i] + LO);
            }
        } else {
            float xs[16];
            *(float4v*)&xs[0]  = *(const float4v*)(aptr + k0);
            *(float4v*)&xs[4]  = *(const float4v*)(aptr + k0 + 4);
            *(float4v*)&xs[8]  = *(const float4v*)(aptr + k0 + 8);
            *(float4v*)&xs[12] = *(const float4v*)(aptr + k0 + 12);
            short8v h0, h1, l0, l1;
            #pragma unroll
            for (int e = 0; e < 8; e++) {
                ushort_t a = f2bf(xs[e]), b = f2bf(xs[8 + e]);
                h0[e] = (short)a; h1[e] = (short)b;
                l0[e] = (short)f2bf(xs[e] - bf2f(a));
                l1[e] = (short)f2bf(xs[8 + e] - bf2f(b));
            }
            *(short8v*)ast_hi0 = h0; *(short8v*)ast_hi1 = h1;
            *(short8v*)ast_lo0 = l0; *(short8v*)ast_lo1 = l1;
        }
        __syncthreads();

        short8v ah[4], al[4], bh[4], bl[4];
        #pragma unroll
        for (int i = 0; i < 4; i++) {
            ah[i] = *(short8v*)&AS2[aoff[i]];
            al[i] = *(short8v*)&AS2[LO + aoff[i]];
            bh[i] = *(short8v*)&BS[boff[i]];
            bl[i] = *(short8v*)&BS[LO + boff[i]];
        }
        if (part != 2) {
            #pragma unroll
            for (int mt = 0; mt < 4; mt++)
                #pragma unroll
                for (int nt = 0; nt < 4; nt++) {
                    acc[mt][nt] = __builtin_amdgcn_mfma_f32_16x16x32_bf16(ah[mt], bh[nt], acc[mt][nt], 0, 0, 0);
                    acc[mt][nt] = __builtin_amdgcn_mfma_f32_16x16x32_bf16(ah[mt], bl[nt], acc[mt][nt], 0, 0, 0);
                    acc[mt][nt] = __builtin_amdgcn_mfma_f32_16x16x32_bf16(al[mt], bh[nt], acc[mt][nt], 0, 0, 0);
                }
        } else {
            #pragma unroll
            for (int mt = 0; mt < 4; mt++)
                #pragma unroll
                for (int nt = 0; nt < 4; nt++)
                    acc[mt][nt] = __builtin_amdgcn_mfma_f32_16x16x32_bf16(ah[mt], bh[nt], acc[mt][nt], 0, 0, 0);
        }
    }

    float bvv[4];
    #pragma unroll
    for (int nt = 0; nt < 4; nt++) bvv[nt] = bias[64 * g + 16 * nt + ln];

    #pragma unroll
    for (int mt = 0; mt < 4; mt++) {
        #pragma unroll
        for (int r = 0; r < 4; r++) {
            int m = m0 + 64 * wr + 16 * mt + 4 * quad + r;
            int bb = m >> 11, s = m & (SEQ - 1);
            size_t hsrow = (size_t)(bb * NH + h) * SEQ + s;
            size_t rowbase = hsrow * HD;
            float vv[4];
            #pragma unroll
            for (int nt = 0; nt < 4; nt++) vv[nt] = acc[mt][nt][r] + bvv[nt];
            if (part == 0) {
                float sq = 0.f;
                #pragma unroll
                for (int nt = 0; nt < 4; nt++) {
                    float v = vv[nt];
                    sq += v * v;
                    float v2 = v * (2.0f * LOG2E);
                    ushort_t hb = f2bf(v2);
                    Qhi[rowbase + 16 * nt + ln] = hb;
                    Qlo[rowbase + 16 * nt + ln] = f2bf(v2 - bf2f(hb));
                }
                sq += __shfl_xor(sq, 1); sq += __shfl_xor(sq, 2);
                sq += __shfl_xor(sq, 4); sq += __shfl_xor(sq, 8);
                if (ln == 0) Qsq[hsrow] = sq * LOG2E - EXP_BIAS;
            } else if (part == 1) {
                float sq = 0.f;
                #pragma unroll
                for (int nt = 0; nt < 4; nt++) {
                    float v = vv[nt];
                    sq += v * v;
                    ushort_t hb = f2bf(v);
                    Khi[rowbase + 16 * nt + ln] = hb;
                    Klo[rowbase + 16 * nt + ln] = f2bf(v - bf2f(hb));
                }
                sq += __shfl_xor(sq, 1); sq += __shfl_xor(sq, 2);
                sq += __shfl_xor(sq, 4); sq += __shfl_xor(sq, 8);
                if (ln == 0) Ksq[hsrow] = sq * LOG2E;
            } else {
                if constexpr (PRE) {
                    #pragma unroll
                    for (int nt = 0; nt < 4; nt++)
                        Vout[((size_t)(bb * NH + h) * 64 + 16 * nt + ln) * SEQ + s] = f2bf(vv[nt]);
                } else {
                    #pragma unroll
                    for (int nt = 0; nt < 4; nt++)
                        Vout[rowbase + 16 * nt + ln] = f2bf(vv[nt]);
                }
            }
        }
    }
}

// ---------------------------------------------------------------------------
// MFMA flash attention: 256 threads, 4 waves x 32 q-rows (round-8 shape).
// FIXES this round:
//  * LDS swizzle keyed on LOW row bits (row&7): 128B rows alias all 32 banks,
//    so chunk = db ^ (row&7) makes 8 consecutive rows hit 8 distinct chunks
//    -> conflict-free fragment reads (old (row>>3)&7 gave 8-way conflicts).
//  * -(ksq+qsq) folded into MFMA accumulator init.
//  * No post-softmax barrier (P rows wave-local: write/read in [32w,32w+32)).
// ---------------------------------------------------------------------------
template<bool PRE>
__global__ __launch_bounds__(256) void attn_mfma_kernel(
    const ushort_t* __restrict__ Qhi, const ushort_t* __restrict__ Qlo,
    const ushort_t* __restrict__ Khi, const ushort_t* __restrict__ Klo,
    const ushort_t* __restrict__ Vsrc,
    const float* __restrict__ Qsq, const float* __restrict__ Ksq,
    ushort_t* __restrict__ vals)
{
    __shared__ ushort_t KS[2 * 64 * 64];           // [hi 4096 | lo 4096]
    __shared__ ushort_t VtS [64 * 64];
    __shared__ ushort_t PsS [128 * 72];
    const int LO = 64 * 64;

    const int t    = threadIdx.x;
    const int w    = t >> 6, lane = t & 63;
    const int quad = (t >> 4) & 3, ln = t & 15;
    const int bh   = blockIdx.y;
    const int q0   = blockIdx.x * 128;
    const size_t base  = (size_t)bh * SEQ * HD;
    const size_t baseS = (size_t)bh * SEQ;

    short8v qhi[2][2], qlo[2][2];
    float nqsq[2][4];
    #pragma unroll
    for (int mt = 0; mt < 2; mt++) {
        size_t ro = base + (size_t)(q0 + 32 * w + 16 * mt + ln) * HD + quad * 8;
        #pragma unroll
        for (int c = 0; c < 2; c++) {
            qhi[mt][c] = *(const short8v*)(Qhi + ro + 32 * c);
            qlo[mt][c] = *(const short8v*)(Qlo + ro + 32 * c);
        }
        float4v q4 = *(const float4v*)(Qsq + baseS + q0 + 32 * w + 16 * mt + 4 * quad);
        #pragma unroll
        for (int r = 0; r < 4; r++) nqsq[mt][r] = -q4[r];
    }

    // K staging (g_l_l, swizzle on global source address, keyed on key&7)
    const ushort_t* gK[2]; ushort_t* lK[2];
    #pragma unroll
    for (int i = 0; i < 2; i++) {
        int c = 256 * i + 64 * w + lane;
        int key = c >> 3, dbp = c & 7;
        gK[i] = Khi + base + (size_t)key * HD + 8 * (dbp ^ (key & 7));
        lK[i] = &KS[(256 * i + 64 * w) * 8];
    }
    const size_t kloff = (size_t)(Klo - Khi);

    const ushort_t* gV[2]; ushort_t* lV[2];
    if constexpr (PRE) {
        #pragma unroll
        for (int i = 0; i < 2; i++) {
            int c = 256 * i + 64 * w + lane;
            int d = c >> 3, kc = c & 7;
            gV[i] = Vsrc + ((size_t)bh * 64 + d) * SEQ + 8 * (kc ^ (d & 7));
            lV[i] = &VtS[(256 * i + 64 * w) * 8];
        }
    }

    float4v accO[2][4];
    float lsum[2][4];
    #pragma unroll
    for (int mt = 0; mt < 2; mt++) {
        #pragma unroll
        for (int nt = 0; nt < 4; nt++) accO[mt][nt] = (float4v){0.f, 0.f, 0.f, 0.f};
        #pragma unroll
        for (int r = 0; r < 4; r++) lsum[mt][r] = 0.f;
    }

    for (int kt = 0; kt < SEQ; kt += 64) {
        __syncthreads();                       // prior-iter KS/VtS reads done
        #pragma unroll
        for (int i = 0; i < 2; i++) {
            gll16(gK[i] + (size_t)kt * HD, lK[i]);
            gll16(gK[i] + (size_t)kt * HD + kloff, lK[i] + LO);
        }
        if constexpr (PRE) {
            #pragma unroll
            for (int i = 0; i < 2; i++)
                gll16(gV[i] + kt, lV[i]);
        } else {
            #pragma unroll
            for (int i = 0; i < 2; i++) {
                int c = t + 256 * i;
                int key = c >> 3, db = c & 7;
                short8v v8 = *(const short8v*)(Vsrc + base + (size_t)(kt + key) * HD + 8 * db);
                #pragma unroll
                for (int e = 0; e < 8; e++) {
                    int col = key ^ (e << 3);   // d = 8db+e, d&7 = e
                    VtS[(8 * db + e) * 64 + col] = (ushort_t)v8[e];
                }
            }
        }
        float ksq_c[4];
        #pragma unroll
        for (int nt = 0; nt < 4; nt++)
            ksq_c[nt] = Ksq[baseS + kt + 16 * nt + ln];
        __syncthreads();

        // scores: acc init = -(ksq+qsq); MFMA adds (2*log2e*q).k
        float4v accS[2][4];
        #pragma unroll
        for (int mt = 0; mt < 2; mt++)
            #pragma unroll
            for (int nt = 0; nt < 4; nt++)
                #pragma unroll
                for (int r = 0; r < 4; r++)
                    accS[mt][nt][r] = nqsq[mt][r] - ksq_c[nt];

        #pragma unroll
        for (int nt = 0; nt < 4; nt++) {
            int keyrow = 16 * nt + ln;
            #pragma unroll
            for (int c = 0; c < 2; c++) {
                int db  = quad + 4 * c;
                int off = keyrow * 64 + ((db ^ (keyrow & 7)) << 3);
                short8v bh_ = *(short8v*)&KS[off];
                short8v bl_ = *(short8v*)&KS[LO + off];
                #pragma unroll
                for (int mt = 0; mt < 2; mt++) {
                    accS[mt][nt] = __builtin_amdgcn_mfma_f32_16x16x32_bf16(qhi[mt][c], bh_, accS[mt][nt], 0, 0, 0);
                    accS[mt][nt] = __builtin_amdgcn_mfma_f32_16x16x32_bf16(qhi[mt][c], bl_, accS[mt][nt], 0, 0, 0);
                    accS[mt][nt] = __builtin_amdgcn_mfma_f32_16x16x32_bf16(qlo[mt][c], bh_, accS[mt][nt], 0, 0, 0);
                }
            }
        }

        // softmax: p = exp2(accS); per-lane l; P -> LDS (wave-local)
        #pragma unroll
        for (int mt = 0; mt < 2; mt++)
            #pragma unroll
            for (int nt = 0; nt < 4; nt++)
                #pragma unroll
                for (int r = 0; r < 4; r++) {
                    float p = exp2f(accS[mt][nt][r]);
                    lsum[mt][r] += p;
                    PsS[(32 * w + 16 * mt + 4 * quad + r) * 72 + 16 * nt + ln] = f2bf(p);
                }
        // no barrier: P rows [32w,32w+32) written and read by wave w only

        // O += P @ V
        #pragma unroll
        for (int c = 0; c < 2; c++) {
            short8v aP[2];
            #pragma unroll
            for (int mt = 0; mt < 2; mt++)
                aP[mt] = *(short8v*)&PsS[(32 * w + 16 * mt + ln) * 72 + quad * 8 + 32 * c];
            #pragma unroll
            for (int nt = 0; nt < 4; nt++) {
                int drow = 16 * nt + ln;
                int db   = quad + 4 * c;
                int off  = drow * 64 + ((db ^ (drow & 7)) << 3);
                short8v bV = *(short8v*)&VtS[off];
                #pragma unroll
                for (int mt = 0; mt < 2; mt++)
                    accO[mt][nt] = __builtin_amdgcn_mfma_f32_16x16x32_bf16(aP[mt], bV, accO[mt][nt], 0, 0, 0);
            }
        }
    }

    const int bb = bh >> 4, h = bh & 15;
    #pragma unroll
    for (int mt = 0; mt < 2; mt++) {
        float inv[4];
        #pragma unroll
        for (int r = 0; r < 4; r++) {
            float s = lsum[mt][r];
            s += __shfl_xor(s, 1); s += __shfl_xor(s, 2);
            s += __shfl_xor(s, 4); s += __shfl_xor(s, 8);
            inv[r] = 1.f / s;
        }
        #pragma unroll
        for (int nt = 0; nt < 4; nt++)
            #pragma unroll
            for (int r = 0; r < 4; r++) {
                int row = q0 + 32 * w + 16 * mt + 4 * quad + r;
                vals[(size_t)(bb * SEQ + row) * DMODEL + h * 64 + 16 * nt + ln] =
                    f2bf(accO[mt][nt][r] * inv[r]);
            }
    }
}

// ---------------------------------------------------------------------------
// Out MFMA GEMM (plain bf16): out = vals @ W_o + b_o, fp32 out.
// ---------------------------------------------------------------------------
__global__ __launch_bounds__(256) void out_mfma_kernel(
    const ushort_t* __restrict__ Ab, const ushort_t* __restrict__ BT,
    const float* __restrict__ bias, float* __restrict__ out)
{
    __shared__ ushort_t AS[128 * 32], BSo[128 * 32];
    const int t = threadIdx.x;
    const int w = t >> 6, lane = t & 63;
    const int quad = (t >> 4) & 3, ln = t & 15;
    const int wr = w >> 1, wc = w & 1;
    const int m0 = blockIdx.y * 128, n0 = blockIdx.x * 128;

    const ushort_t* gA[2]; const ushort_t* gB[2];
    ushort_t *lA[2], *lB[2];
    #pragma unroll
    for (int i = 0; i < 2; i++) {
        int c = 256 * i + 64 * w + lane;
        int r = c >> 2, kbp = c & 3;
        gA[i] = Ab + (size_t)(m0 + r) * 1024 + 8 * (kbp ^ sw4(r));
        gB[i] = BT + (size_t)(n0 + r) * 1024 + 8 * (kbp ^ sw4(r));
        lA[i] = &AS[(256 * i + 64 * w) * 8];
        lB[i] = &BSo[(256 * i + 64 * w) * 8];
    }
    int aoff[4], boff[4];
    #pragma unroll
    for (int i = 0; i < 4; i++) {
        int m_l = 64 * wr + 16 * i + ln;
        aoff[i] = m_l * 32 + ((quad ^ sw4(m_l)) << 3);
        int n_l = 64 * wc + 16 * i + ln;
        boff[i] = n_l * 32 + ((quad ^ sw4(n_l)) << 3);
    }

    float4v acc[4][4];
    #pragma unroll
    for (int i = 0; i < 4; i++)
        #pragma unroll
        for (int j = 0; j < 4; j++) acc[i][j] = (float4v){0.f, 0.f, 0.f, 0.f};

    for (int k0 = 0; k0 < DMODEL; k0 += 32) {
        __syncthreads();
        #pragma unroll
        for (int i = 0; i < 2; i++) {
            gll16(gA[i] + k0, lA[i]);
            gll16(gB[i] + k0, lB[i]);
        }
        __syncthreads();
        short8v a[4], b[4];
        #pragma unroll
        for (int i = 0; i < 4; i++) {
            a[i] = *(short8v*)&AS[aoff[i]];
            b[i] = *(short8v*)&BSo[boff[i]];
        }
        #pragma unroll
        for (int mt = 0; mt < 4; mt++)
            #pragma unroll
            for (int nt = 0; nt < 4; nt++)
                acc[mt][nt] = __builtin_amdgcn_mfma_f32_16x16x32_bf16(a[mt], b[nt], acc[mt][nt], 0, 0, 0);
    }

    #pragma unroll
    for (int nt = 0; nt < 4; nt++) {
        int n = n0 + 64 * wc + 16 * nt + ln;
        float bv = bias[n];
        #pragma unroll
        for (int mt = 0; mt < 4; mt++)
            #pragma unroll
            for (int r = 0; r < 4; r++) {
                int m = m0 + 64 * wr + 16 * mt + 4 * quad + r;
                out[(size_t)m * DMODEL + n] = acc[mt][nt][r] + bv;
            }
    }
}

// ---------------------------------------------------------------------------
// Launch (round-8 layout; PRE if ws fits ~70.5 MiB, else round-7 fallback).
// ---------------------------------------------------------------------------
extern "C" void kernel_launch(void* const* d_in, const int* in_sizes, int n_in,
                              void* d_out, int out_size, void* d_ws, size_t ws_size,
                              hipStream_t stream) {
    const float* x     = (const float*)d_in[0];
    const float* W_qkv = (const float*)d_in[1];
    const float* b_qkv = (const float*)d_in[2];
    const float* W_o   = (const float*)d_in[3];
    const float* b_o   = (const float*)d_in[4];
    float* out = (float*)d_out;

    const size_t WQT = (size_t)N_QKV * DMODEL;
    const size_t WO  = (size_t)DMODEL * DMODEL;
    const size_t QE  = (size_t)NUM_B * NH * SEQ * HD;
    const size_t SQN = (size_t)NUM_B * NH * SEQ;

    const size_t NEED = (2 * WQT + WO + 5 * QE + 2 * QE) * 2 + 2 * SQN * 4;
    const bool pre = (ws_size >= NEED);

    ushort_t* ws     = (ushort_t*)d_ws;
    ushort_t* WqT_hi = ws;
    ushort_t* WqT_lo = WqT_hi + WQT;
    ushort_t* WoT    = WqT_lo + WQT;
    ushort_t* Qhi    = WoT + WO;
    ushort_t* Qlo    = Qhi + QE;
    ushort_t* Khi    = Qlo + QE;
    ushort_t* Klo    = Khi + QE;
    ushort_t* Vx     = Klo + QE;
    float*    Qsq; float* Ksq;
    ushort_t* valsb; ushort_t* Xhi = nullptr; ushort_t* Xlo = nullptr;

    if (pre) {
        Qsq   = (float*)(Vx + QE);
        Ksq   = Qsq + SQN;
        Xhi   = (ushort_t*)(Ksq + SQN);
        Xlo   = Xhi + QE;
        valsb = WqT_hi;
    } else {
        valsb = Vx + QE;
        Qsq   = (float*)(valsb + QE);
        Ksq   = Qsq + SQN;
    }

    prep_kernel<<<pre ? 2048 : 1024, 256, 0, stream>>>(
        W_qkv, W_o, x, WqT_hi, WqT_lo, WoT, Xhi, Xlo);
    if (pre) {
        qkv_mfma_kernel<true><<<dim3(N_QKV / 128, M_TOT / 128), 256, 0, stream>>>(
            x, Xhi, Xlo, WqT_hi, WqT_lo, b_qkv, Qhi, Qlo, Khi, Klo, Vx, Qsq, Ksq);
        attn_mfma_kernel<true><<<dim3(SEQ / 128, NUM_B * NH), 256, 0, stream>>>(
            Qhi, Qlo, Khi, Klo, Vx, Qsq, Ksq, valsb);
    } else {
        qkv_mfma_kernel<false><<<dim3(N_QKV / 128, M_TOT / 128), 256, 0, stream>>>(
            x, nullptr, nullptr, WqT_hi, WqT_lo, b_qkv, Qhi, Qlo, Khi, Klo, Vx, Qsq, Ksq);
        attn_mfma_kernel<false><<<dim3(SEQ / 128, NUM_B * NH), 256, 0, stream>>>(
            Qhi, Qlo, Khi, Klo, Vx, Qsq, Ksq, valsb);
    }
    out_mfma_kernel<<<dim3(DMODEL / 128, M_TOT / 128), 256, 0, stream>>>(
        valsb, WoT, b_o, out);
}

// Round 11
// 322.101 us; speedup vs baseline: 1.1182x; 1.1182x over previous
//
#include <hip/hip_runtime.h>
#include <hip/hip_bf16.h>

// EuclideanAttention: B=2, S=2048, D=1024, H=16, Hd=64. fp32 in/out.
#define NUM_B   2
#define SEQ     2048
#define DMODEL  1024
#define NH      16
#define HD      64
#define M_TOT   (NUM_B * SEQ)      // 4096
#define N_QKV   (3 * DMODEL)       // 3072
#define LOG2E   1.4426950408889634f
#define EXP_BIAS 96.0f             // round-7 verified softmax bias

typedef __attribute__((ext_vector_type(8))) short short8v;
typedef __attribute__((ext_vector_type(4))) float float4v;
typedef unsigned short ushort_t;

__device__ __forceinline__ ushort_t f2bf(float x) {
    unsigned u = __builtin_bit_cast(unsigned, x);
    u = u + 0x7FFFu + ((u >> 16) & 1u);
    return (ushort_t)(u >> 16);
}
__device__ __forceinline__ float bf2f(ushort_t h) {
    unsigned u = ((unsigned)h) << 16;
    return __builtin_bit_cast(float, u);
}
__device__ __forceinline__ void gll16(const void* g, void* l) {
    __builtin_amdgcn_global_load_lds(
        (const __attribute__((address_space(1))) unsigned int*)g,
        (__attribute__((address_space(3))) unsigned int*)l, 16, 0, 0);
}
__device__ __forceinline__ int sw4(int r) { return (r & 3) ^ ((r >> 2) & 3); }

// ---------------------------------------------------------------------------
// Prep: W_qkv -> WqT hi/lo; W_o -> WoT; (PRE) X -> Xhi/Xlo bf16 split.
// ---------------------------------------------------------------------------
__global__ __launch_bounds__(256) void prep_kernel(
    const float* __restrict__ Wq, const float* __restrict__ Wo,
    const float* __restrict__ Xf,
    ushort_t* __restrict__ WqT_hi, ushort_t* __restrict__ WqT_lo,
    ushort_t* __restrict__ WoT,
    ushort_t* __restrict__ Xhi, ushort_t* __restrict__ Xlo)
{
    const int bid = blockIdx.x;
    const int t = threadIdx.x;

    if (bid >= 1024) {             // X split: 1024 blocks x 4096 elements
        size_t base = (size_t)(bid - 1024) * 4096 + t * 16;
        float xs[16];
        *(float4v*)&xs[0]  = *(const float4v*)(Xf + base);
        *(float4v*)&xs[4]  = *(const float4v*)(Xf + base + 4);
        *(float4v*)&xs[8]  = *(const float4v*)(Xf + base + 8);
        *(float4v*)&xs[12] = *(const float4v*)(Xf + base + 12);
        short8v h0, h1, l0, l1;
        #pragma unroll
        for (int e = 0; e < 8; e++) {
            ushort_t a = f2bf(xs[e]), b = f2bf(xs[8 + e]);
            h0[e] = (short)a; h1[e] = (short)b;
            l0[e] = (short)f2bf(xs[e] - bf2f(a));
            l1[e] = (short)f2bf(xs[8 + e] - bf2f(b));
        }
        *(short8v*)(Xhi + base) = h0; *(short8v*)(Xhi + base + 8) = h1;
        *(short8v*)(Xlo + base) = l0; *(short8v*)(Xlo + base + 8) = l1;
        return;
    }

    __shared__ float Tf[64][65];
    const float* src; ushort_t *dhi, *dlo; int N, k0, n0;
    if (bid < 768) {
        int kt = bid / 48, nt = bid % 48;
        src = Wq; N = N_QKV; dhi = WqT_hi; dlo = WqT_lo;
        k0 = kt * 64; n0 = nt * 64;
    } else {
        int tid = bid - 768;
        int kt = tid >> 4, nt = tid & 15;
        src = Wo; N = DMODEL; dhi = WoT; dlo = nullptr;
        k0 = kt * 64; n0 = nt * 64;
    }
    {
        int r = t >> 2, c0 = (t & 3) * 16;
        const float* srow = src + (size_t)(k0 + r) * N + n0 + c0;
        #pragma unroll
        for (int u = 0; u < 4; u++) {
            float4v f = *(const float4v*)(srow + 4 * u);
            #pragma unroll
            for (int e = 0; e < 4; e++) Tf[r][c0 + 4 * u + e] = f[e];
        }
    }
    __syncthreads();
    {
        int nl = t >> 2, kc = (t & 3) * 16;
        short8v h0, h1, l0, l1;
        #pragma unroll
        for (int e = 0; e < 8; e++) {
            float x0 = Tf[kc + e][nl];
            float x1 = Tf[kc + 8 + e][nl];
            ushort_t a = f2bf(x0), b = f2bf(x1);
            h0[e] = (short)a; h1[e] = (short)b;
            l0[e] = (short)f2bf(x0 - bf2f(a));
            l1[e] = (short)f2bf(x1 - bf2f(b));
        }
        ushort_t* o = dhi + (size_t)(n0 + nl) * 1024 + k0 + kc;
        *(short8v*)o = h0; *(short8v*)(o + 8) = h1;
        if (dlo) {
            ushort_t* o2 = dlo + (size_t)(n0 + nl) * 1024 + k0 + kc;
            *(short8v*)o2 = l0; *(short8v*)(o2 + 8) = l1;
        }
    }
}

// ---------------------------------------------------------------------------
// QKV MFMA GEMM (round-8 verified; unchanged).
// ---------------------------------------------------------------------------
template<bool PRE>
__global__ __launch_bounds__(256) void qkv_mfma_kernel(
    const float* __restrict__ X,
    const ushort_t* __restrict__ Xhi, const ushort_t* __restrict__ Xlo,
    const ushort_t* __restrict__ WqT_hi, const ushort_t* __restrict__ WqT_lo,
    const float* __restrict__ bias,
    ushort_t* __restrict__ Qhi, ushort_t* __restrict__ Qlo,
    ushort_t* __restrict__ Khi, ushort_t* __restrict__ Klo,
    ushort_t* __restrict__ Vout,
    float* __restrict__ Qsq, float* __restrict__ Ksq)
{
    __shared__ ushort_t AS2[2 * 128 * 32];
    __shared__ ushort_t BS [2 * 128 * 32];
    const int LO = 128 * 32;
    const int t = threadIdx.x;
    const int w = t >> 6, lane = t & 63;
    const int quad = (t >> 4) & 3, ln = t & 15;
    const int wr = w >> 1, wc = w & 1;
    const int m0 = blockIdx.y * 128, n0 = blockIdx.x * 128;
    const int g = blockIdx.x * 2 + wc;
    const int h = g / 3, part = g % 3;

    const ushort_t* gA[2]; ushort_t* lA[2];
    const float* aptr = nullptr;
    ushort_t *ast_hi0, *ast_hi1, *ast_lo0, *ast_lo1;
    size_t xlo_off = 0;
    if constexpr (PRE) {
        #pragma unroll
        for (int i = 0; i < 2; i++) {
            int c = 256 * i + 64 * w + lane;
            int r = c >> 2, kbp = c & 3;
            gA[i] = Xhi + (size_t)(m0 + r) * 1024 + 8 * (kbp ^ sw4(r));
            lA[i] = &AS2[(256 * i + 64 * w) * 8];
        }
        xlo_off = (size_t)(Xlo - Xhi);
    } else {
        const int arow = t >> 1, akh = t & 1;
        aptr = X + (size_t)(m0 + arow) * DMODEL + 16 * akh;
        const int asw = sw4(arow);
        ast_hi0 = &AS2[arow * 32 + (((2 * akh) ^ asw) << 3)];
        ast_hi1 = &AS2[arow * 32 + (((2 * akh + 1) ^ asw) << 3)];
        ast_lo0 = &AS2[LO + arow * 32 + (((2 * akh) ^ asw) << 3)];
        ast_lo1 = &AS2[LO + arow * 32 + (((2 * akh + 1) ^ asw) << 3)];
    }

    const ushort_t* gB[2]; ushort_t* lB[2];
    #pragma unroll
    for (int i = 0; i < 2; i++) {
        int c = 256 * i + 64 * w + lane;
        int n = c >> 2, kbp = c & 3;
        gB[i] = WqT_hi + (size_t)(n0 + n) * 1024 + 8 * (kbp ^ sw4(n));
        lB[i] = &BS[(256 * i + 64 * w) * 8];
    }
    const size_t lo_goff = (size_t)(WqT_lo - WqT_hi);

    int aoff[4], boff[4];
    #pragma unroll
    for (int i = 0; i < 4; i++) {
        int m_l = 64 * wr + 16 * i + ln;
        aoff[i] = m_l * 32 + ((quad ^ sw4(m_l)) << 3);
        int n_l = 64 * wc + 16 * i + ln;
        boff[i] = n_l * 32 + ((quad ^ sw4(n_l)) << 3);
    }

    float4v acc[4][4];
    #pragma unroll
    for (int i = 0; i < 4; i++)
        #pragma unroll
        for (int j = 0; j < 4; j++) acc[i][j] = (float4v){0.f, 0.f, 0.f, 0.f};

    for (int k0 = 0; k0 < DMODEL; k0 += 32) {
        __syncthreads();
        #pragma unroll
        for (int i = 0; i < 2; i++) {
            gll16(gB[i] + k0, lB[i]);
            gll16(gB[i] + k0 + lo_goff, lB[i] + LO);
        }
        if constexpr (PRE) {
            #pragma unroll
            for (int i = 0; i < 2; i++) {
                gll16(gA[i] + k0, lA[i]);
                gll16(gA[i] + k0 + xlo_off, lA[i] + LO);
            }
        } else {
            float xs[16];
            *(float4v*)&xs[0]  = *(const float4v*)(aptr + k0);
            *(float4v*)&xs[4]  = *(const float4v*)(aptr + k0 + 4);
            *(float4v*)&xs[8]  = *(const float4v*)(aptr + k0 + 8);
            *(float4v*)&xs[12] = *(const float4v*)(aptr + k0 + 12);
            short8v h0, h1, l0, l1;
            #pragma unroll
            for (int e = 0; e < 8; e++) {
                ushort_t a = f2bf(xs[e]), b = f2bf(xs[8 + e]);
                h0[e] = (short)a; h1[e] = (short)b;
                l0[e] = (short)f2bf(xs[e] - bf2f(a));
                l1[e] = (short)f2bf(xs[8 + e] - bf2f(b));
            }
            *(short8v*)ast_hi0 = h0; *(short8v*)ast_hi1 = h1;
            *(short8v*)ast_lo0 = l0; *(short8v*)ast_lo1 = l1;
        }
        __syncthreads();

        short8v ah[4], al[4], bh[4], bl[4];
        #pragma unroll
        for (int i = 0; i < 4; i++) {
            ah[i] = *(short8v*)&AS2[aoff[i]];
            al[i] = *(short8v*)&AS2[LO + aoff[i]];
            bh[i] = *(short8v*)&BS[boff[i]];
            bl[i] = *(short8v*)&BS[LO + boff[i]];
        }
        if (part != 2) {
            #pragma unroll
            for (int mt = 0; mt < 4; mt++)
                #pragma unroll
                for (int nt = 0; nt < 4; nt++) {
                    acc[mt][nt] = __builtin_amdgcn_mfma_f32_16x16x32_bf16(ah[mt], bh[nt], acc[mt][nt], 0, 0, 0);
                    acc[mt][nt] = __builtin_amdgcn_mfma_f32_16x16x32_bf16(ah[mt], bl[nt], acc[mt][nt], 0, 0, 0);
                    acc[mt][nt] = __builtin_amdgcn_mfma_f32_16x16x32_bf16(al[mt], bh[nt], acc[mt][nt], 0, 0, 0);
                }
        } else {
            #pragma unroll
            for (int mt = 0; mt < 4; mt++)
                #pragma unroll
                for (int nt = 0; nt < 4; nt++)
                    acc[mt][nt] = __builtin_amdgcn_mfma_f32_16x16x32_bf16(ah[mt], bh[nt], acc[mt][nt], 0, 0, 0);
        }
    }

    float bvv[4];
    #pragma unroll
    for (int nt = 0; nt < 4; nt++) bvv[nt] = bias[64 * g + 16 * nt + ln];

    #pragma unroll
    for (int mt = 0; mt < 4; mt++) {
        #pragma unroll
        for (int r = 0; r < 4; r++) {
            int m = m0 + 64 * wr + 16 * mt + 4 * quad + r;
            int bb = m >> 11, s = m & (SEQ - 1);
            size_t hsrow = (size_t)(bb * NH + h) * SEQ + s;
            size_t rowbase = hsrow * HD;
            float vv[4];
            #pragma unroll
            for (int nt = 0; nt < 4; nt++) vv[nt] = acc[mt][nt][r] + bvv[nt];
            if (part == 0) {
                float sq = 0.f;
                #pragma unroll
                for (int nt = 0; nt < 4; nt++) {
                    float v = vv[nt];
                    sq += v * v;
                    float v2 = v * (2.0f * LOG2E);
                    ushort_t hb = f2bf(v2);
                    Qhi[rowbase + 16 * nt + ln] = hb;
                    Qlo[rowbase + 16 * nt + ln] = f2bf(v2 - bf2f(hb));
                }
                sq += __shfl_xor(sq, 1); sq += __shfl_xor(sq, 2);
                sq += __shfl_xor(sq, 4); sq += __shfl_xor(sq, 8);
                if (ln == 0) Qsq[hsrow] = sq * LOG2E - EXP_BIAS;
            } else if (part == 1) {
                float sq = 0.f;
                #pragma unroll
                for (int nt = 0; nt < 4; nt++) {
                    float v = vv[nt];
                    sq += v * v;
                    ushort_t hb = f2bf(v);
                    Khi[rowbase + 16 * nt + ln] = hb;
                    Klo[rowbase + 16 * nt + ln] = f2bf(v - bf2f(hb));
                }
                sq += __shfl_xor(sq, 1); sq += __shfl_xor(sq, 2);
                sq += __shfl_xor(sq, 4); sq += __shfl_xor(sq, 8);
                if (ln == 0) Ksq[hsrow] = sq * LOG2E;
            } else {
                if constexpr (PRE) {
                    #pragma unroll
                    for (int nt = 0; nt < 4; nt++)
                        Vout[((size_t)(bb * NH + h) * 64 + 16 * nt + ln) * SEQ + s] = f2bf(vv[nt]);
                } else {
                    #pragma unroll
                    for (int nt = 0; nt < 4; nt++)
                        Vout[rowbase + 16 * nt + ln] = f2bf(vv[nt]);
                }
            }
        }
    }
}

// ---------------------------------------------------------------------------
// MFMA flash attention: EXACT round-8 register structure (zero-init accS,
// inline -ksq-qsq in exp2, post-softmax barrier kept, VGPR 128 / 2 blk/CU)
// with ONLY the swizzle fix applied: chunk = db ^ (row & 7). 128B LDS rows
// alias all 32 banks, so keying on low row bits makes 8 consecutive rows hit
// 8 distinct chunks -> conflict-free fragment reads (round-10 verified:
// conflicts 1.99e7 -> 1.05e6).
// ---------------------------------------------------------------------------
template<bool PRE>
__global__ __launch_bounds__(256) void attn_mfma_kernel(
    const ushort_t* __restrict__ Qhi, const ushort_t* __restrict__ Qlo,
    const ushort_t* __restrict__ Khi, const ushort_t* __restrict__ Klo,
    const ushort_t* __restrict__ Vsrc,
    const float* __restrict__ Qsq, const float* __restrict__ Ksq,
    ushort_t* __restrict__ vals)
{
    __shared__ ushort_t KS[2 * 64 * 64];           // [hi 4096 | lo 4096]
    __shared__ ushort_t VtS [64 * 64];
    __shared__ ushort_t PsS [128 * 72];
    const int LO = 64 * 64;

    const int t    = threadIdx.x;
    const int w    = t >> 6, lane = t & 63;
    const int quad = (t >> 4) & 3, ln = t & 15;
    const int bh   = blockIdx.y;
    const int q0   = blockIdx.x * 128;
    const size_t base  = (size_t)bh * SEQ * HD;
    const size_t baseS = (size_t)bh * SEQ;

    short8v qhi[2][2], qlo[2][2];
    float4v qsq4[2];
    #pragma unroll
    for (int mt = 0; mt < 2; mt++) {
        size_t ro = base + (size_t)(q0 + 32 * w + 16 * mt + ln) * HD + quad * 8;
        #pragma unroll
        for (int c = 0; c < 2; c++) {
            qhi[mt][c] = *(const short8v*)(Qhi + ro + 32 * c);
            qlo[mt][c] = *(const short8v*)(Qlo + ro + 32 * c);
        }
        qsq4[mt] = *(const float4v*)(Qsq + baseS + q0 + 32 * w + 16 * mt + 4 * quad);
    }

    // K staging (g_l_l, swizzle on global source address, keyed on key&7)
    const ushort_t* gK[2]; ushort_t* lK[2];
    #pragma unroll
    for (int i = 0; i < 2; i++) {
        int c = 256 * i + 64 * w + lane;
        int key = c >> 3, dbp = c & 7;
        gK[i] = Khi + base + (size_t)key * HD + 8 * (dbp ^ (key & 7));
        lK[i] = &KS[(256 * i + 64 * w) * 8];
    }
    const size_t kloff = (size_t)(Klo - Khi);

    const ushort_t* gV[2]; ushort_t* lV[2];
    if constexpr (PRE) {
        #pragma unroll
        for (int i = 0; i < 2; i++) {
            int c = 256 * i + 64 * w + lane;
            int d = c >> 3, kc = c & 7;
            gV[i] = Vsrc + ((size_t)bh * 64 + d) * SEQ + 8 * (kc ^ (d & 7));
            lV[i] = &VtS[(256 * i + 64 * w) * 8];
        }
    }

    float4v accO[2][4];
    float lsum[2][4];
    #pragma unroll
    for (int mt = 0; mt < 2; mt++) {
        #pragma unroll
        for (int nt = 0; nt < 4; nt++) accO[mt][nt] = (float4v){0.f, 0.f, 0.f, 0.f};
        #pragma unroll
        for (int r = 0; r < 4; r++) lsum[mt][r] = 0.f;
    }

    for (int kt = 0; kt < SEQ; kt += 64) {
        __syncthreads();                       // prior-iter KS/VtS reads done
        #pragma unroll
        for (int i = 0; i < 2; i++) {
            gll16(gK[i] + (size_t)kt * HD, lK[i]);
            gll16(gK[i] + (size_t)kt * HD + kloff, lK[i] + LO);
        }
        if constexpr (PRE) {
            #pragma unroll
            for (int i = 0; i < 2; i++)
                gll16(gV[i] + kt, lV[i]);
        } else {
            #pragma unroll
            for (int i = 0; i < 2; i++) {
                int c = t + 256 * i;
                int key = c >> 3, db = c & 7;
                short8v v8 = *(const short8v*)(Vsrc + base + (size_t)(kt + key) * HD + 8 * db);
                #pragma unroll
                for (int e = 0; e < 8; e++) {
                    int col = key ^ (e << 3);   // d = 8db+e, d&7 = e
                    VtS[(8 * db + e) * 64 + col] = (ushort_t)v8[e];
                }
            }
        }
        float ksq_c[4];
        #pragma unroll
        for (int nt = 0; nt < 4; nt++)
            ksq_c[nt] = Ksq[baseS + kt + 16 * nt + ln];
        __syncthreads();

        // scores: (2*log2e*q).k split MFMA (zero-init acc, round-8 structure)
        float4v accS[2][4];
        #pragma unroll
        for (int mt = 0; mt < 2; mt++)
            #pragma unroll
            for (int nt = 0; nt < 4; nt++) accS[mt][nt] = (float4v){0.f, 0.f, 0.f, 0.f};

        #pragma unroll
        for (int nt = 0; nt < 4; nt++) {
            int keyrow = 16 * nt + ln;
            #pragma unroll
            for (int c = 0; c < 2; c++) {
                int db  = quad + 4 * c;
                int off = keyrow * 64 + ((db ^ (keyrow & 7)) << 3);
                short8v bh_ = *(short8v*)&KS[off];
                short8v bl_ = *(short8v*)&KS[LO + off];
                #pragma unroll
                for (int mt = 0; mt < 2; mt++) {
                    accS[mt][nt] = __builtin_amdgcn_mfma_f32_16x16x32_bf16(qhi[mt][c], bh_, accS[mt][nt], 0, 0, 0);
                    accS[mt][nt] = __builtin_amdgcn_mfma_f32_16x16x32_bf16(qhi[mt][c], bl_, accS[mt][nt], 0, 0, 0);
                    accS[mt][nt] = __builtin_amdgcn_mfma_f32_16x16x32_bf16(qlo[mt][c], bh_, accS[mt][nt], 0, 0, 0);
                }
            }
        }

        // softmax: p = exp2(acc - ksq - qsq); per-lane l; P -> LDS
        #pragma unroll
        for (int mt = 0; mt < 2; mt++)
            #pragma unroll
            for (int nt = 0; nt < 4; nt++)
                #pragma unroll
                for (int r = 0; r < 4; r++) {
                    float p = exp2f(accS[mt][nt][r] - ksq_c[nt] - qsq4[mt][r]);
                    lsum[mt][r] += p;
                    PsS[(32 * w + 16 * mt + 4 * quad + r) * 72 + 16 * nt + ln] = f2bf(p);
                }
        __syncthreads();

        // O += P @ V
        #pragma unroll
        for (int c = 0; c < 2; c++) {
            short8v aP[2];
            #pragma unroll
            for (int mt = 0; mt < 2; mt++)
                aP[mt] = *(short8v*)&PsS[(32 * w + 16 * mt + ln) * 72 + quad * 8 + 32 * c];
            #pragma unroll
            for (int nt = 0; nt < 4; nt++) {
                int drow = 16 * nt + ln;
                int db   = quad + 4 * c;
                int off  = drow * 64 + ((db ^ (drow & 7)) << 3);
                short8v bV = *(short8v*)&VtS[off];
                #pragma unroll
                for (int mt = 0; mt < 2; mt++)
                    accO[mt][nt] = __builtin_amdgcn_mfma_f32_16x16x32_bf16(aP[mt], bV, accO[mt][nt], 0, 0, 0);
            }
        }
    }

    const int bb = bh >> 4, h = bh & 15;
    #pragma unroll
    for (int mt = 0; mt < 2; mt++) {
        float inv[4];
        #pragma unroll
        for (int r = 0; r < 4; r++) {
            float s = lsum[mt][r];
            s += __shfl_xor(s, 1); s += __shfl_xor(s, 2);
            s += __shfl_xor(s, 4); s += __shfl_xor(s, 8);
            inv[r] = 1.f / s;
        }
        #pragma unroll
        for (int nt = 0; nt < 4; nt++)
            #pragma unroll
            for (int r = 0; r < 4; r++) {
                int row = q0 + 32 * w + 16 * mt + 4 * quad + r;
                vals[(size_t)(bb * SEQ + row) * DMODEL + h * 64 + 16 * nt + ln] =
                    f2bf(accO[mt][nt][r] * inv[r]);
            }
    }
}

// ---------------------------------------------------------------------------
// Out MFMA GEMM (plain bf16): out = vals @ W_o + b_o, fp32 out.
// ---------------------------------------------------------------------------
__global__ __launch_bounds__(256) void out_mfma_kernel(
    const ushort_t* __restrict__ Ab, const ushort_t* __restrict__ BT,
    const float* __restrict__ bias, float* __restrict__ out)
{
    __shared__ ushort_t AS[128 * 32], BSo[128 * 32];
    const int t = threadIdx.x;
    const int w = t >> 6, lane = t & 63;
    const int quad = (t >> 4) & 3, ln = t & 15;
    const int wr = w >> 1, wc = w & 1;
    const int m0 = blockIdx.y * 128, n0 = blockIdx.x * 128;

    const ushort_t* gA[2]; const ushort_t* gB[2];
    ushort_t *lA[2], *lB[2];
    #pragma unroll
    for (int i = 0; i < 2; i++) {
        int c = 256 * i + 64 * w + lane;
        int r = c >> 2, kbp = c & 3;
        gA[i] = Ab + (size_t)(m0 + r) * 1024 + 8 * (kbp ^ sw4(r));
        gB[i] = BT + (size_t)(n0 + r) * 1024 + 8 * (kbp ^ sw4(r));
        lA[i] = &AS[(256 * i + 64 * w) * 8];
        lB[i] = &BSo[(256 * i + 64 * w) * 8];
    }
    int aoff[4], boff[4];
    #pragma unroll
    for (int i = 0; i < 4; i++) {
        int m_l = 64 * wr + 16 * i + ln;
        aoff[i] = m_l * 32 + ((quad ^ sw4(m_l)) << 3);
        int n_l = 64 * wc + 16 * i + ln;
        boff[i] = n_l * 32 + ((quad ^ sw4(n_l)) << 3);
    }

    float4v acc[4][4];
    #pragma unroll
    for (int i = 0; i < 4; i++)
        #pragma unroll
        for (int j = 0; j < 4; j++) acc[i][j] = (float4v){0.f, 0.f, 0.f, 0.f};

    for (int k0 = 0; k0 < DMODEL; k0 += 32) {
        __syncthreads();
        #pragma unroll
        for (int i = 0; i < 2; i++) {
            gll16(gA[i] + k0, lA[i]);
            gll16(gB[i] + k0, lB[i]);
        }
        __syncthreads();
        short8v a[4], b[4];
        #pragma unroll
        for (int i = 0; i < 4; i++) {
            a[i] = *(short8v*)&AS[aoff[i]];
            b[i] = *(short8v*)&BSo[boff[i]];
        }
        #pragma unroll
        for (int mt = 0; mt < 4; mt++)
            #pragma unroll
            for (int nt = 0; nt < 4; nt++)
                acc[mt][nt] = __builtin_amdgcn_mfma_f32_16x16x32_bf16(a[mt], b[nt], acc[mt][nt], 0, 0, 0);
    }

    #pragma unroll
    for (int nt = 0; nt < 4; nt++) {
        int n = n0 + 64 * wc + 16 * nt + ln;
        float bv = bias[n];
        #pragma unroll
        for (int mt = 0; mt < 4; mt++)
            #pragma unroll
            for (int r = 0; r < 4; r++) {
                int m = m0 + 64 * wr + 16 * mt + 4 * quad + r;
                out[(size_t)m * DMODEL + n] = acc[mt][nt][r] + bv;
            }
    }
}

// ---------------------------------------------------------------------------
// Launch (round-8 layout; PRE if ws fits ~70.5 MiB, else round-7 fallback).
// ---------------------------------------------------------------------------
extern "C" void kernel_launch(void* const* d_in, const int* in_sizes, int n_in,
                              void* d_out, int out_size, void* d_ws, size_t ws_size,
                              hipStream_t stream) {
    const float* x     = (const float*)d_in[0];
    const float* W_qkv = (const float*)d_in[1];
    const float* b_qkv = (const float*)d_in[2];
    const float* W_o   = (const float*)d_in[3];
    const float* b_o   = (const float*)d_in[4];
    float* out = (float*)d_out;

    const size_t WQT = (size_t)N_QKV * DMODEL;
    const size_t WO  = (size_t)DMODEL * DMODEL;
    const size_t QE  = (size_t)NUM_B * NH * SEQ * HD;
    const size_t SQN = (size_t)NUM_B * NH * SEQ;

    const size_t NEED = (2 * WQT + WO + 5 * QE + 2 * QE) * 2 + 2 * SQN * 4;
    const bool pre = (ws_size >= NEED);

    ushort_t* ws     = (ushort_t*)d_ws;
    ushort_t* WqT_hi = ws;
    ushort_t* WqT_lo = WqT_hi + WQT;
    ushort_t* WoT    = WqT_lo + WQT;
    ushort_t* Qhi    = WoT + WO;
    ushort_t* Qlo    = Qhi + QE;
    ushort_t* Khi    = Qlo + QE;
    ushort_t* Klo    = Khi + QE;
    ushort_t* Vx     = Klo + QE;
    float*    Qsq; float* Ksq;
    ushort_t* valsb; ushort_t* Xhi = nullptr; ushort_t* Xlo = nullptr;

    if (pre) {
        Qsq   = (float*)(Vx + QE);
        Ksq   = Qsq + SQN;
        Xhi   = (ushort_t*)(Ksq + SQN);
        Xlo   = Xhi + QE;
        valsb = WqT_hi;
    } else {
        valsb = Vx + QE;
        Qsq   = (float*)(valsb + QE);
        Ksq   = Qsq + SQN;
    }

    prep_kernel<<<pre ? 2048 : 1024, 256, 0, stream>>>(
        W_qkv, W_o, x, WqT_hi, WqT_lo, WoT, Xhi, Xlo);
    if (pre) {
        qkv_mfma_kernel<true><<<dim3(N_QKV / 128, M_TOT / 128), 256, 0, stream>>>(
            x, Xhi, Xlo, WqT_hi, WqT_lo, b_qkv, Qhi, Qlo, Khi, Klo, Vx, Qsq, Ksq);
        attn_mfma_kernel<true><<<dim3(SEQ / 128, NUM_B * NH), 256, 0, stream>>>(
            Qhi, Qlo, Khi, Klo, Vx, Qsq, Ksq, valsb);
    } else {
        qkv_mfma_kernel<false><<<dim3(N_QKV / 128, M_TOT / 128), 256, 0, stream>>>(
            x, nullptr, nullptr, WqT_hi, WqT_lo, b_qkv, Qhi, Qlo, Khi, Klo, Vx, Qsq, Ksq);
        attn_mfma_kernel<false><<<dim3(SEQ / 128, NUM_B * NH), 256, 0, stream>>>(
            Qhi, Qlo, Khi, Klo, Vx, Qsq, Ksq, valsb);
    }
    out_mfma_kernel<<<dim3(DMODEL / 128, M_TOT / 128), 256, 0, stream>>>(
        valsb, WoT, b_o, out);
}